// Round 5
// baseline (442.096 us; speedup 1.0000x reference)
//
#include <hip/hip_runtime.h>

#define N_NODES 50000
#define N_EDGES 800000
#define IN_F 96
#define HID_F 128
#define OUT_F 64
#define T_S 8
#define SCAN_B 196  // ceil(50000/256)

typedef __attribute__((ext_vector_type(8))) short short8;
typedef __attribute__((ext_vector_type(4))) float float4v;
typedef __attribute__((ext_vector_type(2))) unsigned int uint2v;
typedef __attribute__((ext_vector_type(4))) unsigned int uint4v;

__device__ __forceinline__ float bf2f(unsigned short h) {
    unsigned u = ((unsigned)h) << 16;
    float f;
    __builtin_memcpy(&f, &u, 4);
    return f;
}
__device__ __forceinline__ unsigned short f2bf(float f) {
    unsigned u;
    __builtin_memcpy(&u, &f, 4);
    unsigned r = (u + 0x7fffu + ((u >> 16) & 1u)) >> 16;  // RTNE
    return (unsigned short)r;
}
__device__ __forceinline__ float bf_lo(unsigned u) {
    unsigned v = u << 16;
    float f;
    __builtin_memcpy(&f, &v, 4);
    return f;
}
__device__ __forceinline__ float bf_hi(unsigned u) {
    unsigned v = u & 0xffff0000u;
    float f;
    __builtin_memcpy(&f, &v, 4);
    return f;
}

// ---------------- fused prep: count | x->bf16 | weight prep ----------------
// blocks [0,3125): edge count; [3125,7813): xb convert; [7813,8453): wprep
__global__ __launch_bounds__(256) void k_prep(const int* __restrict__ dst,
                                              int* __restrict__ cnt,
                                              const float* __restrict__ x,
                                              unsigned short* __restrict__ xb,
                                              const float* __restrict__ W1,
                                              const float* __restrict__ W2,
                                              const float* __restrict__ m1,
                                              const float* __restrict__ m2,
                                              unsigned short* __restrict__ wf) {
    int b = blockIdx.x;
    if (b < 3125) {
        int e = b * 256 + threadIdx.x;  // 3125*256 == 800000 exact
        atomicAdd(&cnt[dst[e]], 1);
    } else if (b < 7813) {
        int i = (b - 3125) * 256 + threadIdx.x;
        int idx = i * 4;
        if (idx < N_NODES * IN_F) {
            float4 v = *(const float4*)(x + idx);
            uint2v r;
            r.x = (unsigned)f2bf(v.x) | ((unsigned)f2bf(v.y) << 16);
            r.y = (unsigned)f2bf(v.z) | ((unsigned)f2bf(v.w) << 16);
            *(uint2v*)(xb + idx) = r;
        }
    } else {
        int gid = (b - 7813) * 256 + threadIdx.x;  // 640*256 == 163840 exact
        int t = gid / 20480;
        int idx = gid % 20480;
        float val;
        if (idx < 12288) {
            int j = idx & 7, lane = (idx >> 3) & 63, fr = idx >> 9;  // fr 0..23
            int kk = fr >> 3, nt = fr & 7;
            int k = kk * 32 + (lane >> 4) * 8 + j;
            int n = nt * 16 + (lane & 15);
            val = W1[k * HID_F + n] * m1[((size_t)t * IN_F + k) * HID_F + n];
        } else {
            int i2 = idx - 12288;
            int j = i2 & 7, lane = (i2 >> 3) & 63, fr = i2 >> 9;  // fr 0..15
            int kk = fr >> 2, ot = fr & 3;
            int k = kk * 32 + (lane >> 4) * 8 + j;
            int o = ot * 16 + (lane & 15);
            val = W2[k * OUT_F + o] * m2[((size_t)t * HID_F + k) * OUT_F + o];
        }
        wf[gid] = f2bf(val);
    }
}

// ---------------- hierarchical scan ----------------
__global__ __launch_bounds__(256) void k_scan1(const int* __restrict__ cnt,
                                               int* __restrict__ excl,
                                               int* __restrict__ blockSums) {
    __shared__ int buf[256];
    int tid = threadIdx.x;
    int idx = blockIdx.x * 256 + tid;
    int v = (idx < N_NODES) ? cnt[idx] : 0;
    buf[tid] = v;
    __syncthreads();
    for (int off = 1; off < 256; off <<= 1) {
        int t = buf[tid];
        int u = (tid >= off) ? buf[tid - off] : 0;
        __syncthreads();
        buf[tid] = t + u;
        __syncthreads();
    }
    int incl = buf[tid];
    if (idx < N_NODES) excl[idx] = incl - v;
    if (tid == 255) blockSums[blockIdx.x] = incl;
}

__global__ __launch_bounds__(256) void k_scan2(const int* __restrict__ blockSums,
                                               int* __restrict__ blockOff) {
    __shared__ int buf[256];
    int tid = threadIdx.x;
    int v = (tid < SCAN_B) ? blockSums[tid] : 0;
    buf[tid] = v;
    __syncthreads();
    for (int off = 1; off < 256; off <<= 1) {
        int t = buf[tid];
        int u = (tid >= off) ? buf[tid - off] : 0;
        __syncthreads();
        buf[tid] = t + u;
        __syncthreads();
    }
    if (tid < SCAN_B) blockOff[tid] = buf[tid] - v;
}

__global__ __launch_bounds__(256) void k_scan3(const int* __restrict__ excl,
                                               const int* __restrict__ blockOff,
                                               int* __restrict__ row_ptr,
                                               int* __restrict__ cursor) {
    int idx = blockIdx.x * 256 + threadIdx.x;
    if (idx < N_NODES) {
        int p = excl[idx] + blockOff[blockIdx.x];
        row_ptr[idx] = p;
        cursor[idx] = p;
    }
    if (idx == 0) row_ptr[N_NODES] = N_EDGES;
}

__global__ void k_fill(const int* __restrict__ src, const int* __restrict__ dst,
                       const float* __restrict__ ew, int* __restrict__ cursor,
                       int* __restrict__ csr_src, float* __restrict__ csr_w) {
    int e = blockIdx.x * 256 + threadIdx.x;
    if (e < N_EDGES) {
        int d = dst[e];
        int pos = atomicAdd(&cursor[d], 1);
        csr_src[pos] = src[e];
        csr_w[pos] = ew[e];
    }
}

// ---------------- SPMM1: wave per node, masked unroll-16, no scalar tail ----------------
__global__ __launch_bounds__(256) void k_spmm1(const unsigned short* __restrict__ xb,
                                               const int* __restrict__ row_ptr,
                                               const int* __restrict__ csr_src,
                                               const float* __restrict__ csr_w,
                                               unsigned short* __restrict__ agg1) {
    int wave = threadIdx.x >> 6, lane = threadIdx.x & 63;
    int node = blockIdx.x * 4 + wave;
    if (lane >= 48) return;  // 48 dwords per 96-bf16 row
    int beg = row_ptr[node], end = row_ptr[node + 1];
    int last = end - 1;
    const unsigned* xrow = (const unsigned*)xb;
    float a0 = 0.f, a1 = 0.f;
    for (int e = beg; e < end; e += 16) {
        int s[16];
        float wv[16];
        unsigned d[16];
#pragma unroll
        for (int i = 0; i < 16; i++) {
            int ee = e + i;
            int ii = (ee < end) ? ee : last;
            s[i] = __builtin_nontemporal_load(&csr_src[ii]);
            float wl = __builtin_nontemporal_load(&csr_w[ii]);
            wv[i] = (ee < end) ? wl : 0.f;
        }
#pragma unroll
        for (int i = 0; i < 16; i++) d[i] = xrow[(size_t)s[i] * 48 + lane];
#pragma unroll
        for (int i = 0; i < 16; i++) {
            a0 = fmaf(wv[i], bf_lo(d[i]), a0);
            a1 = fmaf(wv[i], bf_hi(d[i]), a1);
        }
    }
    ((unsigned*)agg1)[(size_t)node * 48 + lane] =
        (unsigned)f2bf(a0) | ((unsigned)f2bf(a1) << 16);
}

// ------------- Fused GEMM: p_t = relu(agg1 @ W1m_t) @ W2m_t, bf16 out [node][t][o] -------------
__global__ __launch_bounds__(256) void k_gemm(const unsigned short* __restrict__ agg1,
                                              const unsigned short* __restrict__ wfrags,
                                              unsigned short* __restrict__ P, int tBase,
                                              int nodeStride, int tMul) {
    __shared__ __align__(16) unsigned short ldsW[20480];     // 40 KB
    __shared__ __align__(16) unsigned short ldsH[4][2176];   // 4 waves x [16][136] bf16
    int t = tBase + blockIdx.y;
    const uint4v* wsrc = (const uint4v*)(wfrags + (size_t)t * 20480);
    uint4v* wdst = (uint4v*)ldsW;
    for (int i = threadIdx.x; i < 2560; i += 256) wdst[i] = wsrc[i];
    __syncthreads();

    int wave = threadIdx.x >> 6, lane = threadIdx.x & 63;
    int quad = lane >> 4, l15 = lane & 15;
    int node = blockIdx.x * 64 + wave * 16 + l15;
    bool v = node < N_NODES;

    short8 a[3];
    if (v) {
        const unsigned short* ap = agg1 + (size_t)node * IN_F;
        a[0] = *(const short8*)(ap + 0 * 32 + quad * 8);
        a[1] = *(const short8*)(ap + 1 * 32 + quad * 8);
        a[2] = *(const short8*)(ap + 2 * 32 + quad * 8);
    } else {
        short8 z = {0, 0, 0, 0, 0, 0, 0, 0};
        a[0] = z; a[1] = z; a[2] = z;
    }

    for (int nt = 0; nt < 8; nt++) {
        float4v acc = {0.f, 0.f, 0.f, 0.f};
        for (int kk = 0; kk < 3; kk++) {
            short8 w = *(const short8*)&ldsW[(kk * 8 + nt) * 512 + lane * 8];
            acc = __builtin_amdgcn_mfma_f32_16x16x32_bf16(w, a[kk], acc, 0, 0, 0);
        }
        unsigned h0 = f2bf(fmaxf(acc[0], 0.f));
        unsigned h1 = f2bf(fmaxf(acc[1], 0.f));
        unsigned h2 = f2bf(fmaxf(acc[2], 0.f));
        unsigned h3 = f2bf(fmaxf(acc[3], 0.f));
        uint2v pk;
        pk.x = h0 | (h1 << 16);
        pk.y = h2 | (h3 << 16);
        *(uint2v*)&ldsH[wave][l15 * 136 + nt * 16 + quad * 4] = pk;
    }

    short8 hf[4];
    for (int kk = 0; kk < 4; kk++)
        hf[kk] = *(const short8*)&ldsH[wave][l15 * 136 + kk * 32 + quad * 8];

    unsigned short* Pt = P + (size_t)node * nodeStride + (size_t)t * tMul;
    for (int ot = 0; ot < 4; ot++) {
        float4v acc = {0.f, 0.f, 0.f, 0.f};
        for (int kk = 0; kk < 4; kk++) {
            short8 w = *(const short8*)&ldsW[12288 + (kk * 4 + ot) * 512 + lane * 8];
            acc = __builtin_amdgcn_mfma_f32_16x16x32_bf16(w, hf[kk], acc, 0, 0, 0);
        }
        if (v) {
            uint2v pk;
            pk.x = (unsigned)f2bf(acc[0]) | ((unsigned)f2bf(acc[1]) << 16);
            pk.y = (unsigned)f2bf(acc[2]) | ((unsigned)f2bf(acc[3]) << 16);
            __builtin_nontemporal_store(pk, (uint2v*)(Pt + ot * 16 + quad * 4));
        }
    }
}

// ------------- SPMM2 batched: P [node][t][o] (1KB row), wave per node, masked unroll-8 -------------
__global__ __launch_bounds__(256) void k_spmm2(const unsigned short* __restrict__ P,
                                               const int* __restrict__ row_ptr,
                                               const int* __restrict__ csr_src,
                                               const float* __restrict__ csr_w,
                                               float* __restrict__ out) {
    int wave = threadIdx.x >> 6, lane = threadIdx.x & 63;
    int node = blockIdx.x * 4 + wave;
    int beg = row_ptr[node], end = row_ptr[node + 1];
    int last = end - 1;
    const uint4v* Pl = (const uint4v*)P + lane;  // row = 64 uint4v
    float acc[8] = {0.f, 0.f, 0.f, 0.f, 0.f, 0.f, 0.f, 0.f};
    for (int e = beg; e < end; e += 8) {
        int s[8];
        float wv[8];
        uint4v d[8];
#pragma unroll
        for (int i = 0; i < 8; i++) {
            int ee = e + i;
            int ii = (ee < end) ? ee : last;
            s[i] = __builtin_nontemporal_load(&csr_src[ii]);
            float wl = __builtin_nontemporal_load(&csr_w[ii]);
            wv[i] = (ee < end) ? wl : 0.f;
        }
#pragma unroll
        for (int i = 0; i < 8; i++) d[i] = Pl[(size_t)s[i] * 64];
#pragma unroll
        for (int i = 0; i < 8; i++) {
            acc[0] = fmaf(wv[i], bf_lo(d[i].x), acc[0]);
            acc[1] = fmaf(wv[i], bf_hi(d[i].x), acc[1]);
            acc[2] = fmaf(wv[i], bf_lo(d[i].y), acc[2]);
            acc[3] = fmaf(wv[i], bf_hi(d[i].y), acc[3]);
            acc[4] = fmaf(wv[i], bf_lo(d[i].z), acc[4]);
            acc[5] = fmaf(wv[i], bf_hi(d[i].z), acc[5]);
            acc[6] = fmaf(wv[i], bf_lo(d[i].w), acc[6]);
            acc[7] = fmaf(wv[i], bf_hi(d[i].w), acc[7]);
        }
    }
    // lane covers value indices lane*8..+7 of the [t][o] row: t = lane>>3, o = (lane&7)*8
    int t = lane >> 3, o = (lane & 7) * 8;
    float* op = out + ((size_t)t * N_NODES + node) * OUT_F + o;
    float4v v0 = {acc[0], acc[1], acc[2], acc[3]};
    float4v v1 = {acc[4], acc[5], acc[6], acc[7]};
    __builtin_nontemporal_store(v0, (float4v*)op);
    __builtin_nontemporal_store(v1, (float4v*)(op + 4));
}

// per-sample fallback (small workspace): P layout [node][64]
__global__ __launch_bounds__(512) void k_spmm2_1t(const unsigned short* __restrict__ P,
                                                  const int* __restrict__ row_ptr,
                                                  const int* __restrict__ csr_src,
                                                  const float* __restrict__ csr_w,
                                                  float* __restrict__ out) {
    int node = blockIdx.x * 8 + (threadIdx.x >> 6);
    int o = threadIdx.x & 63;
    if (node >= N_NODES) return;
    int beg = row_ptr[node], end = row_ptr[node + 1];
    const unsigned short* Pt = P + o;
    float a0 = 0.f, a1 = 0.f, a2 = 0.f, a3 = 0.f;
    int e = beg;
    for (; e + 3 < end; e += 4) {
        int s0 = csr_src[e], s1 = csr_src[e + 1], s2 = csr_src[e + 2], s3 = csr_src[e + 3];
        float w0 = csr_w[e], w1 = csr_w[e + 1], w2 = csr_w[e + 2], w3 = csr_w[e + 3];
        a0 += w0 * bf2f(Pt[(size_t)s0 * OUT_F]);
        a1 += w1 * bf2f(Pt[(size_t)s1 * OUT_F]);
        a2 += w2 * bf2f(Pt[(size_t)s2 * OUT_F]);
        a3 += w3 * bf2f(Pt[(size_t)s3 * OUT_F]);
    }
    for (; e < end; e++) a0 += csr_w[e] * bf2f(Pt[(size_t)csr_src[e] * OUT_F]);
    out[(size_t)node * OUT_F + o] = a0 + a1 + a2 + a3;
}

extern "C" void kernel_launch(void* const* d_in, const int* in_sizes, int n_in,
                              void* d_out, int out_size, void* d_ws, size_t ws_size,
                              hipStream_t stream) {
    const float* x = (const float*)d_in[0];
    const float* ew = (const float*)d_in[1];
    const float* W1 = (const float*)d_in[2];
    const float* W2 = (const float*)d_in[3];
    const float* m1 = (const float*)d_in[4];
    const float* m2 = (const float*)d_in[5];
    const int* src = (const int*)d_in[6];
    const int* dst = (const int*)d_in[7];
    float* out = (float*)d_out;

    char* w = (char*)d_ws;
    size_t off = 0;
    auto alloc = [&](size_t bytes) -> void* {
        void* p = (void*)(w + off);
        off += (bytes + 255) & ~(size_t)255;
        return p;
    };
    int* cnt = (int*)alloc((size_t)N_NODES * 4);
    int* row_ptr = (int*)alloc((size_t)(N_NODES + 1) * 4);
    int* cursor = (int*)alloc((size_t)N_NODES * 4);
    int* excl = (int*)alloc((size_t)N_NODES * 4);
    int* blockSums = (int*)alloc((size_t)SCAN_B * 4);
    int* blockOff = (int*)alloc((size_t)SCAN_B * 4);
    int* csr_src = (int*)alloc((size_t)N_EDGES * 4);
    float* csr_w = (float*)alloc((size_t)N_EDGES * 4);
    unsigned short* agg1 = (unsigned short*)alloc((size_t)N_NODES * IN_F * 2);
    unsigned short* wf = (unsigned short*)alloc((size_t)T_S * 20480 * 2);

    size_t xbBytes = (size_t)N_NODES * IN_F * 2;
    size_t pBytesBatched = (size_t)T_S * N_NODES * OUT_F * 2;
    unsigned short* xb = (unsigned short*)alloc(xbBytes);
    bool batched = ws_size >= off + pBytesBatched;
    unsigned short* P = (unsigned short*)alloc(batched ? pBytesBatched
                                                       : (size_t)N_NODES * OUT_F * 2);

    hipMemsetAsync(cnt, 0, (size_t)N_NODES * 4, stream);
    k_prep<<<8453, 256, 0, stream>>>(dst, cnt, x, xb, W1, W2, m1, m2, wf);
    k_scan1<<<SCAN_B, 256, 0, stream>>>(cnt, excl, blockSums);
    k_scan2<<<1, 256, 0, stream>>>(blockSums, blockOff);
    k_scan3<<<SCAN_B, 256, 0, stream>>>(excl, blockOff, row_ptr, cursor);
    k_fill<<<N_EDGES / 256, 256, 0, stream>>>(src, dst, ew, cursor, csr_src, csr_w);
    k_spmm1<<<N_NODES / 4, 256, 0, stream>>>(xb, row_ptr, csr_src, csr_w, agg1);

    if (batched) {
        k_gemm<<<dim3(782, 8), 256, 0, stream>>>(agg1, wf, P, 0, T_S * OUT_F, OUT_F);
        k_spmm2<<<N_NODES / 4, 256, 0, stream>>>(P, row_ptr, csr_src, csr_w, out);
    } else {
        for (int t = 0; t < T_S; t++) {
            k_gemm<<<dim3(782, 1), 256, 0, stream>>>(agg1, wf, P, t, OUT_F, 0);
            k_spmm2_1t<<<6250, 512, 0, stream>>>(P, row_ptr, csr_src, csr_w,
                                                 out + (size_t)t * N_NODES * OUT_F);
        }
    }
}